// Round 5
// baseline (1202.394 us; speedup 1.0000x reference)
//
#include <hip/hip_runtime.h>

// ---- problem constants ----
#define BATCH 16
#define RB    8
#define CITIES 1023
#define NODES 1024
#define HDIM  64
#define H2DIM 128
#define KTOT  3072          // 3 poly terms * 1024 (c padded to 1024)

// sigmoid(x) ~= 0.5 + C1*x + C3*x^3 on [-1,1], max err ~1.3e-4
#define C1f 0.24944119f
#define C3f (-0.01850586f)

typedef __bf16    bf16x8 __attribute__((ext_vector_type(8)));
typedef _Float16  f16x8  __attribute__((ext_vector_type(8)));
typedef float     f32x4  __attribute__((ext_vector_type(4)));
typedef float     f32x2  __attribute__((ext_vector_type(2)));

__device__ __forceinline__ f32x4 mfma16(bf16x8 a, bf16x8 b, f32x4 c){
    return __builtin_amdgcn_mfma_f32_16x16x32_bf16(a, b, c, 0, 0, 0);
}
__device__ __forceinline__ f32x4 mfma16h(f16x8 a, f16x8 b, f32x4 c){
    return __builtin_amdgcn_mfma_f32_16x16x32_f16(a, b, c, 0, 0, 0);
}
__device__ __forceinline__ unsigned short f2b(float f){
    __bf16 b = (__bf16)f;
    return __builtin_bit_cast(unsigned short, b);
}
__device__ __forceinline__ float b2f(unsigned short u){
    unsigned int t = ((unsigned int)u) << 16;
    return __builtin_bit_cast(float, t);
}
__device__ __forceinline__ unsigned short f2h(float f){
    _Float16 h = (_Float16)f;
    return __builtin_bit_cast(unsigned short, h);
}
__device__ __forceinline__ float h2f(unsigned short u){
    return (float)__builtin_bit_cast(_Float16, u);
}

// ---------------- kernel: x_a[b,n] = max_r x_a_state*(assign_prev+action) ----------------
__global__ __launch_bounds__(256) void xa_k(const float* __restrict__ xs,
        const float* __restrict__ ap, const float* __restrict__ act,
        float* __restrict__ xa){
    int idx = blockIdx.x*256 + threadIdx.x;       // 16384
    int b = idx >> 10, n = idx & 1023;
    float m = -1e30f;
    #pragma unroll
    for(int r=0;r<RB;r++){
        size_t o = (((size_t)b*RB + r)<<10) + n;
        m = fmaxf(m, xs[o]*(ap[o]+act[o]));
    }
    xa[idx] = m;
}

// ---------------- presence MLP + softmax; packed-f32 (v_pk_fma_f32) inner loop -----------
__global__ __launch_bounds__(128) void presence_k(const float* __restrict__ edge,
        const float* __restrict__ W1, const float* __restrict__ W2,
        const float* __restrict__ avail,
        unsigned short* __restrict__ P, unsigned short* __restrict__ D){
    int c = blockIdx.x, b = blockIdx.y;
    int tid = threadIdx.x;
    __shared__ float4 Wl[64];
    __shared__ float red[2];
    if(tid < 64) Wl[tid] = make_float4(W1[tid], W1[64+tid], W1[128+tid], W2[tid]);
    __syncthreads();
    f32x2 E0[4], E1[4], E2[4], ACC[4];
    size_t ebase = (((size_t)b*CITIES + c)<<10)*3;
    #pragma unroll
    for(int j=0;j<8;j++){
        int n = tid + j*128;
        size_t ea = ebase + (size_t)n*3;
        E0[j>>1][j&1] = edge[ea];
        E1[j>>1][j&1] = edge[ea+1];
        E2[j>>1][j&1] = edge[ea+2];
    }
    #pragma unroll
    for(int j2=0;j2<4;j2++) ACC[j2] = (f32x2){0.f,0.f};
    const f32x2 z2 = {0.f,0.f};
    for(int h=0;h<64;h++){
        float4 w = Wl[h];
        f32x2 wx = {w.x,w.x}, wy = {w.y,w.y}, wz = {w.z,w.z}, ww = {w.w,w.w};
        #pragma unroll
        for(int j2=0;j2<4;j2++){
            f32x2 a = __builtin_elementwise_fma(E0[j2], wx,
                      __builtin_elementwise_fma(E1[j2], wy, E2[j2]*wz));
            a = __builtin_elementwise_max(a, z2);
            ACC[j2] = __builtin_elementwise_fma(a, ww, ACC[j2]);
        }
    }
    float lg[8], ex[8];
    #pragma unroll
    for(int j=0;j<8;j++){
        int n = tid + j*128;
        float h2 = fmaxf(ACC[j>>1][j&1], 0.f);     // relu; /TAU with TAU=1
        float mk = (n==c) ? 0.f : avail[(b<<10)+n];
        lg[j] = h2*mk - (1.f-mk)*1e10f;
    }
    int wv = tid>>6, ln = tid&63;
    float mx = -1e30f;
    #pragma unroll
    for(int j=0;j<8;j++) mx = fmaxf(mx, lg[j]);
    for(int o=32;o>0;o>>=1) mx = fmaxf(mx, __shfl_xor(mx,o,64));
    if(ln==0) red[wv]=mx;
    __syncthreads();
    mx = fmaxf(red[0],red[1]);
    __syncthreads();
    float s = 0.f;
    #pragma unroll
    for(int j=0;j<8;j++){ ex[j] = expf(lg[j]-mx); s += ex[j]; }
    for(int o=32;o>0;o>>=1) s += __shfl_xor(s,o,64);
    if(ln==0) red[wv]=s;
    __syncthreads();
    s = red[0]+red[1];
    float inv = 1.f/s;
    size_t pbase = ((size_t)b*CITIES + c)<<10;
    #pragma unroll
    for(int j=0;j<8;j++){
        int n = tid + j*128;
        P[pbase+n] = f2h(ex[j]*inv);
        D[pbase+n] = f2h(E0[j>>1][j&1]);
    }
}

// ------- build A' [b][i][3*1024] fp16 = {p, p*d, p*d^3} transposed -----------------------
__global__ __launch_bounds__(256) void abuild_k(const unsigned short* __restrict__ P,
        const unsigned short* __restrict__ D, unsigned short* __restrict__ A){
    int ct = blockIdx.x, nt = blockIdx.y, b = blockIdx.z;
    int tid = threadIdx.x;
    __shared__ unsigned short Pt[32][36];
    __shared__ unsigned short Dt[32][36];
    {
        int crow = tid>>3, ng = (tid&7)<<2;
        int c = ct*32 + crow;
        if(c < CITIES){
            size_t o = (((size_t)b*CITIES + c)<<10) + nt*32 + ng;
            *(ushort4*)&Pt[crow][ng] = *(const ushort4*)&P[o];
            *(ushort4*)&Dt[crow][ng] = *(const ushort4*)&D[o];
        } else {
            ushort4 z; z.x=0;z.y=0;z.z=0;z.w=0;
            *(ushort4*)&Pt[crow][ng] = z;
            *(ushort4*)&Dt[crow][ng] = z;
        }
    }
    __syncthreads();
    int nrow = tid>>3, cg = (tid&7)<<2;
    ushort4 w0, w1, w2;
    #pragma unroll
    for(int j=0;j<4;j++){
        float p = h2f(Pt[cg+j][nrow]);
        float d = h2f(Dt[cg+j][nrow]);
        float d3 = d*d*d;
        ((unsigned short*)&w0)[j] = f2h(p);
        ((unsigned short*)&w1)[j] = f2h(p*d);
        ((unsigned short*)&w2)[j] = f2h(p*d3);
    }
    size_t abase = ((size_t)(b<<10) + nt*32 + nrow)*KTOT + ct*32 + cg;
    *(ushort4*)&A[abase]      = w0;
    *(ushort4*)&A[abase+1024] = w1;
    *(ushort4*)&A[abase+2048] = w2;
}

// ---------------- initial B'^T [b][h][kc] = q_k(h) * U0[b][c][h] (fp16) ------------------
__global__ __launch_bounds__(256) void binit_k(const float* __restrict__ U0,
        const float* __restrict__ We, unsigned short* __restrict__ BT, int nout){
    int kc = blockIdx.x*256 + threadIdx.x;   // 0..3071
    int h = blockIdx.y, b = blockIdx.z;
    int k = kc >> 10, c = kc & 1023;
    float we = We[h];
    float q = (k==0) ? 0.5f : (k==1 ? C1f*we : C3f*we*we*we);
    float u = (c < CITIES) ? U0[(((size_t)b<<10) + c)*nout + h] : 0.f;
    BT[((size_t)(b*nout + h))*KTOT + kc] = f2h(q*u);
}

#define SR 72
#define KSTEPS 24   // 3072 / 128

// ================= FUSED T1: full-K GEMM (M=64,N=64) + epilogue in one kernel ===========
// grid (16 mt, 16 b), 256 thr. LDS: staging A 16KB + B 16KB; epilogue aliased 36.9KB.
template<bool LAST>
__global__ __launch_bounds__(256) void gfused1_k(const unsigned short* __restrict__ Ap,
        const unsigned short* __restrict__ BT,
        const float* __restrict__ Wl1a, const float* __restrict__ Wl1b,
        const float* __restrict__ Wx1a, const float* __restrict__ Wx1b,
        const float* __restrict__ We1a, const float* __restrict__ xa,
        unsigned short* __restrict__ Bnext, float* __restrict__ ua, float* __restrict__ ub){
    int mt = blockIdx.x, b = blockIdx.y;
    int tid = threadIdx.x, wave=tid>>6, lane=tid&63, quad=lane>>4, l16=lane&15;
    __shared__ __align__(16) char smem[64*SR*2*4*sizeof(unsigned short)]; // 36,864 B
    unsigned short* At = (unsigned short*)smem;          // 64 x 128 (16 KB)
    unsigned short* Bt = At + 64*128;                    // 64 x 128 (16 KB)
    unsigned short* Lh = (unsigned short*)smem;          // epilogue aliases
    unsigned short* Ll = Lh + 64*SR;
    unsigned short* Wh = Ll + 64*SR;
    unsigned short* Wo = Wh + 64*SR;

    f32x4 gacc[4];
    #pragma unroll
    for(int nt=0;nt<4;nt++) gacc[nt] = (f32x4){0.f,0.f,0.f,0.f};

    // staging map: q in 0..3 -> (row = q*16 + tid>>4, ch = tid&15)
    int srow = tid>>4, sch = tid&15;
    const unsigned short* gA = Ap + ((size_t)(b<<10) + mt*64)*KTOT + sch*8;
    const unsigned short* gB = BT + ((size_t)b*64)*KTOT + sch*8;
    int swz = (sch ^ srow)*8;       // swizzled chunk pos (row&15 == srow)
    uint4 ra[4], rb[4];
    #pragma unroll
    for(int q=0;q<4;q++){
        ra[q] = *(const uint4*)(gA + (size_t)(q*16+srow)*KTOT);
        rb[q] = *(const uint4*)(gB + (size_t)(q*16+srow)*KTOT);
    }
    for(int kk=0;kk<KSTEPS;kk++){
        __syncthreads();   // previous step's frag reads done -> LDS free
        #pragma unroll
        for(int q=0;q<4;q++){
            *(uint4*)&At[(q*16+srow)*128 + swz] = ra[q];
            *(uint4*)&Bt[(q*16+srow)*128 + swz] = rb[q];
        }
        if(kk+1 < KSTEPS){
            #pragma unroll
            for(int q=0;q<4;q++){
                ra[q] = *(const uint4*)(gA + (size_t)(q*16+srow)*KTOT + (kk+1)*128);
                rb[q] = *(const uint4*)(gB + (size_t)(q*16+srow)*KTOT + (kk+1)*128);
            }
        }
        __syncthreads();
        #pragma unroll
        for(int kb=0;kb<4;kb++){
            f16x8 a = *(const f16x8*)&At[(wave*16 + l16)*128 + (((kb*4+quad)^l16)<<3)];
            #pragma unroll
            for(int nt=0;nt<4;nt++){
                f16x8 bf = *(const f16x8*)&Bt[(nt*16 + l16)*128 + (((kb*4+quad)^l16)<<3)];
                gacc[nt] = mfma16h(a, bf, gacc[nt]);
            }
        }
    }
    // ---- epilogue: l = gacc; compute u = relu(l@Wl + xa*Wx); emit Bnext / ua,ub ----
    __syncthreads();   // staging LDS -> epilogue alias
    {
        int k = tid>>2, n0 = (tid&3)*16;
        for(int j=0;j<16;j++){
            float w = Wl1a[k*64 + n0 + j];
            unsigned short hh = f2b(w);
            Wh[(n0+j)*SR + k] = hh;
            Wo[(n0+j)*SR + k] = f2b(w - b2f(hh));
        }
        #pragma unroll
        for(int nt=0;nt<4;nt++){
            #pragma unroll
            for(int rr=0;rr<4;rr++){
                int row = wave*16 + quad*4 + rr;
                int col = nt*16 + l16;
                float v = gacc[nt][rr];
                unsigned short hh = f2b(v);
                Lh[row*SR + col] = hh;
                Ll[row*SR + col] = f2b(v - b2f(hh));
            }
        }
    }
    __syncthreads();
    f32x4 zero = {0.f,0.f,0.f,0.f};
    f32x4 acc[4] = {zero,zero,zero,zero};
    #pragma unroll
    for(int kc=0;kc<2;kc++){
        bf16x8 ah = *(const bf16x8*)&Lh[(wave*16+l16)*SR + kc*32 + quad*8];
        bf16x8 al = *(const bf16x8*)&Ll[(wave*16+l16)*SR + kc*32 + quad*8];
        #pragma unroll
        for(int nt=0;nt<4;nt++){
            bf16x8 bh = *(const bf16x8*)&Wh[(nt*16+l16)*SR + kc*32 + quad*8];
            bf16x8 bl = *(const bf16x8*)&Wo[(nt*16+l16)*SR + kc*32 + quad*8];
            acc[nt] = mfma16(ah, bh, acc[nt]);
            acc[nt] = mfma16(ah, bl, acc[nt]);
            acc[nt] = mfma16(al, bh, acc[nt]);
        }
    }
    int gi = mt*64 + wave*16 + quad*4;
    float4 xav = *(const float4*)&xa[(b<<10) + gi];
    float xr[4] = {xav.x, xav.y, xav.z, xav.w};
    if(!LAST){
        #pragma unroll
        for(int nt=0;nt<4;nt++){
            int h = nt*16 + l16;
            float wx = Wx1a[h];
            float we = We1a[h];
            float q1 = C1f*we, q2 = C3f*we*we*we;
            ushort4 w0,w1,w2;
            #pragma unroll
            for(int rr=0;rr<4;rr++){
                float u = fmaxf(acc[nt][rr] + xr[rr]*wx, 0.f);
                bool pad = (gi+rr == 1023);
                ((unsigned short*)&w0)[rr] = pad?(unsigned short)0:f2h(0.5f*u);
                ((unsigned short*)&w1)[rr] = pad?(unsigned short)0:f2h(q1*u);
                ((unsigned short*)&w2)[rr] = pad?(unsigned short)0:f2h(q2*u);
            }
            size_t base = ((size_t)(b*64 + h))*KTOT + gi;
            *(ushort4*)&Bnext[base]      = w0;
            *(ushort4*)&Bnext[base+1024] = w1;
            *(ushort4*)&Bnext[base+2048] = w2;
        }
    } else {
        #pragma unroll
        for(int nt=0;nt<4;nt++){
            int h = nt*16+l16; float wx = Wx1a[h];
            #pragma unroll
            for(int rr=0;rr<4;rr++)
                ua[(((size_t)b<<10)+gi+rr)*64 + h] = fmaxf(acc[nt][rr] + xr[rr]*wx, 0.f);
        }
        __syncthreads();
        { int k = tid>>2, n0 = (tid&3)*16;
          for(int j=0;j<16;j++){
              float w = Wl1b[k*64 + n0 + j];
              unsigned short hh = f2b(w);
              Wh[(n0+j)*SR + k] = hh;
              Wo[(n0+j)*SR + k] = f2b(w - b2f(hh));
          } }
        __syncthreads();
        f32x4 acc2[4] = {zero,zero,zero,zero};
        #pragma unroll
        for(int kc=0;kc<2;kc++){
            bf16x8 ah = *(const bf16x8*)&Lh[(wave*16+l16)*SR + kc*32 + quad*8];
            bf16x8 al = *(const bf16x8*)&Ll[(wave*16+l16)*SR + kc*32 + quad*8];
            #pragma unroll
            for(int nt=0;nt<4;nt++){
                bf16x8 bh = *(const bf16x8*)&Wh[(nt*16+l16)*SR + kc*32 + quad*8];
                bf16x8 bl = *(const bf16x8*)&Wo[(nt*16+l16)*SR + kc*32 + quad*8];
                acc2[nt] = mfma16(ah, bh, acc2[nt]);
                acc2[nt] = mfma16(ah, bl, acc2[nt]);
                acc2[nt] = mfma16(al, bh, acc2[nt]);
            }
        }
        #pragma unroll
        for(int nt=0;nt<4;nt++){
            int h = nt*16+l16; float wx = Wx1b[h];
            #pragma unroll
            for(int rr=0;rr<4;rr++)
                ub[(((size_t)b<<10)+gi+rr)*64 + h] = fmaxf(acc2[nt][rr] + xr[rr]*wx, 0.f);
        }
    }
}

// ---------------- x2 = concat(ua,ub) @ W_x_2  (hi/lo MFMA, 2 K-phases) -------------------
__global__ __launch_bounds__(256) void x2_k(const float* __restrict__ ua,
        const float* __restrict__ ub, const float* __restrict__ Wx2,
        float* __restrict__ x2){
    int mt = blockIdx.x, b = blockIdx.y;
    int i0 = mt*64;
    int tid = threadIdx.x, wave=tid>>6, lane=tid&63, quad=lane>>4, l16=lane&15;
    __shared__ __align__(16) unsigned short Uh[64*SR], Ul[64*SR];
    __shared__ __align__(16) unsigned short Wh[128*SR], Wo[128*SR];
    f32x4 zero = {0.f,0.f,0.f,0.f};
    f32x4 acc[8];
    #pragma unroll
    for(int nt=0;nt<8;nt++) acc[nt]=zero;
    for(int ph=0; ph<2; ph++){
        if(ph) __syncthreads();
        {
            int k = tid>>2, n0 = (tid&3)*32;
            for(int j=0;j<32;j++){
                float w = Wx2[(ph*64 + k)*128 + n0 + j];
                unsigned short hh = f2b(w);
                Wh[(n0+j)*SR + k] = hh;
                Wo[(n0+j)*SR + k] = f2b(w - b2f(hh));
            }
            int i = tid>>2, c0 = (tid&3)*16;
            const float* src = (ph ? ub : ua) + (((size_t)b<<10)+i0+i)*64 + c0;
            #pragma unroll
            for(int j=0;j<4;j++){
                float4 v = *(const float4*)(src + j*4);
                float vv[4] = {v.x, v.y, v.z, v.w};
                #pragma unroll
                for(int t=0;t<4;t++){
                    unsigned short hh = f2b(vv[t]);
                    Uh[i*SR + c0 + j*4 + t] = hh;
                    Ul[i*SR + c0 + j*4 + t] = f2b(vv[t] - b2f(hh));
                }
            }
        }
        __syncthreads();
        #pragma unroll
        for(int kc=0;kc<2;kc++){
            bf16x8 ah = *(const bf16x8*)&Uh[(wave*16+l16)*SR + kc*32 + quad*8];
            bf16x8 al = *(const bf16x8*)&Ul[(wave*16+l16)*SR + kc*32 + quad*8];
            #pragma unroll
            for(int nt=0;nt<8;nt++){
                bf16x8 bh = *(const bf16x8*)&Wh[(nt*16+l16)*SR + kc*32 + quad*8];
                bf16x8 bl = *(const bf16x8*)&Wo[(nt*16+l16)*SR + kc*32 + quad*8];
                acc[nt] = mfma16(ah, bh, acc[nt]);
                acc[nt] = mfma16(ah, bl, acc[nt]);
                acc[nt] = mfma16(al, bh, acc[nt]);
            }
        }
    }
    int gi = i0 + wave*16 + quad*4;
    #pragma unroll
    for(int nt=0;nt<8;nt++){
        int h = nt*16 + l16;
        #pragma unroll
        for(int rr=0;rr<4;rr++)
            x2[(((size_t)b<<10)+gi+rr)*128 + h] = acc[nt][rr];
    }
}

// ================= FUSED T2: full-K GEMM (M=64,N=128) + epilogue =========================
// LDS: staging A 16KB + B 32KB = 48KB; epilogue aliased 55.3KB.
template<bool LAST>
__global__ __launch_bounds__(256) void gfused2_k(const unsigned short* __restrict__ Ap,
        const unsigned short* __restrict__ BT,
        const float* __restrict__ Wl2, const float* __restrict__ x2,
        const float* __restrict__ We2, const float* __restrict__ WQ,
        unsigned short* __restrict__ Bnext, float* __restrict__ out){
    int mt = blockIdx.x, b = blockIdx.y;
    int tid = threadIdx.x, wave=tid>>6, lane=tid&63, quad=lane>>4, l16=lane&15;
    __shared__ __align__(16) char smem[(64*SR*2 + 128*SR*2)*sizeof(unsigned short)]; // 55,296 B
    unsigned short* At = (unsigned short*)smem;          // 64 x 128 (16 KB)
    unsigned short* Bt = At + 64*128;                    // 128 x 128 (32 KB)
    unsigned short* Lh = (unsigned short*)smem;          // epilogue aliases
    unsigned short* Ll = Lh + 64*SR;
    unsigned short* Wh = Ll + 64*SR;
    unsigned short* Wo = Wh + 128*SR;
    __shared__ float red[4];

    f32x4 gacc[8];
    #pragma unroll
    for(int nt=0;nt<8;nt++) gacc[nt] = (f32x4){0.f,0.f,0.f,0.f};

    int srow = tid>>4, sch = tid&15;
    const unsigned short* gA = Ap + ((size_t)(b<<10) + mt*64)*KTOT + sch*8;
    const unsigned short* gB = BT + ((size_t)b*128)*KTOT + sch*8;
    int swz = (sch ^ srow)*8;
    uint4 ra[4], rb[8];
    #pragma unroll
    for(int q=0;q<4;q++) ra[q] = *(const uint4*)(gA + (size_t)(q*16+srow)*KTOT);
    #pragma unroll
    for(int q=0;q<8;q++) rb[q] = *(const uint4*)(gB + (size_t)(q*16+srow)*KTOT);
    for(int kk=0;kk<KSTEPS;kk++){
        __syncthreads();
        #pragma unroll
        for(int q=0;q<4;q++) *(uint4*)&At[(q*16+srow)*128 + swz] = ra[q];
        #pragma unroll
        for(int q=0;q<8;q++) *(uint4*)&Bt[(q*16+srow)*128 + swz] = rb[q];
        if(kk+1 < KSTEPS){
            #pragma unroll
            for(int q=0;q<4;q++) ra[q] = *(const uint4*)(gA + (size_t)(q*16+srow)*KTOT + (kk+1)*128);
            #pragma unroll
            for(int q=0;q<8;q++) rb[q] = *(const uint4*)(gB + (size_t)(q*16+srow)*KTOT + (kk+1)*128);
        }
        __syncthreads();
        #pragma unroll
        for(int kb=0;kb<4;kb++){
            f16x8 a = *(const f16x8*)&At[(wave*16 + l16)*128 + (((kb*4+quad)^l16)<<3)];
            #pragma unroll
            for(int nt=0;nt<8;nt++){
                f16x8 bf = *(const f16x8*)&Bt[(nt*16 + l16)*128 + (((kb*4+quad)^l16)<<3)];
                gacc[nt] = mfma16h(a, bf, gacc[nt]);
            }
        }
    }
    // ---- epilogue: gamma = relu(l@Wl2 + x2); emit Bnext / Q ----
    f32x4 zero = {0.f,0.f,0.f,0.f};
    f32x4 acc[8];
    #pragma unroll
    for(int nt=0;nt<8;nt++) acc[nt]=zero;
    for(int ph=0; ph<2; ph++){
        __syncthreads();   // staging (ph0) or previous-phase reads (ph1) done
        {
            int k = tid>>2, n0 = (tid&3)*32;
            for(int j=0;j<32;j++){
                float w = Wl2[(ph*64 + k)*128 + n0 + j];
                unsigned short hh = f2b(w);
                Wh[(n0+j)*SR + k] = hh;
                Wo[(n0+j)*SR + k] = f2b(w - b2f(hh));
            }
            #pragma unroll
            for(int nt=0;nt<4;nt++){
                #pragma unroll
                for(int rr=0;rr<4;rr++){
                    int row = wave*16 + quad*4 + rr;
                    int col = nt*16 + l16;
                    float v = gacc[ph*4+nt][rr];
                    unsigned short hh = f2b(v);
                    Lh[row*SR + col] = hh;
                    Ll[row*SR + col] = f2b(v - b2f(hh));
                }
            }
        }
        __syncthreads();
        #pragma unroll
        for(int kc=0;kc<2;kc++){
            bf16x8 ah = *(const bf16x8*)&Lh[(wave*16+l16)*SR + kc*32 + quad*8];
            bf16x8 al = *(const bf16x8*)&Ll[(wave*16+l16)*SR + kc*32 + quad*8];
            #pragma unroll
            for(int nt=0;nt<8;nt++){
                bf16x8 bh = *(const bf16x8*)&Wh[(nt*16+l16)*SR + kc*32 + quad*8];
                bf16x8 bl = *(const bf16x8*)&Wo[(nt*16+l16)*SR + kc*32 + quad*8];
                acc[nt] = mfma16(ah, bh, acc[nt]);
                acc[nt] = mfma16(ah, bl, acc[nt]);
                acc[nt] = mfma16(al, bh, acc[nt]);
            }
        }
    }
    int gi = mt*64 + wave*16 + quad*4;
    float qp = 0.f;
    #pragma unroll
    for(int nt=0;nt<8;nt++){
        int h = nt*16 + l16;
        float g[4];
        #pragma unroll
        for(int rr=0;rr<4;rr++)
            g[rr] = fmaxf(acc[nt][rr] + x2[(((size_t)b<<10)+gi+rr)*128 + h], 0.f);
        if(!LAST){
            float we = We2[h];
            float q1 = C1f*we, q2 = C3f*we*we*we;
            ushort4 w0,w1,w2;
            #pragma unroll
            for(int rr=0;rr<4;rr++){
                bool pad = (gi+rr == 1023);
                ((unsigned short*)&w0)[rr] = pad?(unsigned short)0:f2h(0.5f*g[rr]);
                ((unsigned short*)&w1)[rr] = pad?(unsigned short)0:f2h(q1*g[rr]);
                ((unsigned short*)&w2)[rr] = pad?(unsigned short)0:f2h(q2*g[rr]);
            }
            size_t base = ((size_t)(b*128 + h))*KTOT + gi;
            *(ushort4*)&Bnext[base]      = w0;
            *(ushort4*)&Bnext[base+1024] = w1;
            *(ushort4*)&Bnext[base+2048] = w2;
        } else {
            float wq = WQ[h];
            #pragma unroll
            for(int rr=0;rr<4;rr++) qp = fmaf(g[rr], wq, qp);
        }
    }
    if(LAST){
        for(int o=32;o>0;o>>=1) qp += __shfl_xor(qp,o,64);
        if(lane==0) red[wave]=qp;
        __syncthreads();
        if(tid==0) atomicAdd(&out[b], red[0]+red[1]+red[2]+red[3]);
    }
}

// ---------------- host launch ------------------------------------------------------------
extern "C" void kernel_launch(void* const* d_in, const int* in_sizes, int n_in,
                              void* d_out, int out_size, void* d_ws, size_t ws_size,
                              hipStream_t stream){
    (void)in_sizes; (void)n_in; (void)out_size; (void)ws_size;
    const float* xs   = (const float*)d_in[0];
    const float* ap   = (const float*)d_in[1];
    const float* act  = (const float*)d_in[2];
    const float* edge = (const float*)d_in[3];
    const float* avail= (const float*)d_in[4];
    const float* ua0  = (const float*)d_in[5];
    const float* g0   = (const float*)d_in[7];
    const float* W1p  = (const float*)d_in[8];
    const float* W2p  = (const float*)d_in[9];
    const float* Wx1a = (const float*)d_in[10];
    const float* We1a = (const float*)d_in[11];
    const float* Wl1a = (const float*)d_in[12];
    const float* Wx1b = (const float*)d_in[13];
    const float* Wl1b = (const float*)d_in[15];
    const float* Wx2  = (const float*)d_in[16];
    const float* We2  = (const float*)d_in[17];
    const float* Wl2  = (const float*)d_in[18];
    const float* WQ   = (const float*)d_in[19];
    float* out = (float*)d_out;

    char* ws = (char*)d_ws;
    // A' (persistent): 16*1024*3072*2 = 100,663,296 B
    unsigned short* Abuf = (unsigned short*)ws;
    char* r2 = ws + 100663296;
    // P/D (fp16) live only until abuild; aliased with B' buffers after:
    unsigned short* Pbuf = (unsigned short*)r2;                      // 33,521,664
    unsigned short* Dbuf = (unsigned short*)(r2 + 33521664);         // 33,521,664 (ends 67,043,328)
    unsigned short* BT1a = (unsigned short*)r2;                      //  6,291,456
    unsigned short* BT1b = (unsigned short*)(r2 + 6291456);          //  6,291,456
    unsigned short* BT2a = (unsigned short*)(r2 + 12582912);         // 12,582,912
    unsigned short* BT2b = (unsigned short*)(r2 + 25165824);         // 12,582,912 (ends 37,748,736)
    float* uaB           = (float*)(r2 + 67108864);                  //  4,194,304
    float* ubB           = (float*)(r2 + 71303168);                  //  4,194,304
    float* x2B           = (float*)(r2 + 75497472);                  //  8,388,608
    float* xaB           = (float*)(r2 + 83886080);                  //     65,536
    unsigned short* BT1[2] = {BT1a, BT1b};
    unsigned short* BT2[2] = {BT2a, BT2b};

    hipMemsetAsync(d_out, 0, BATCH*sizeof(float), stream);
    xa_k<<<64,256,0,stream>>>(xs, ap, act, xaB);
    presence_k<<<dim3(CITIES,BATCH),128,0,stream>>>(edge, W1p, W2p, avail, Pbuf, Dbuf);
    abuild_k<<<dim3(32,32,BATCH),256,0,stream>>>(Pbuf, Dbuf, Abuf);
    binit_k<<<dim3(12,64,BATCH),256,0,stream>>>(ua0, We1a, BT1[0], 64);
    for(int it=0; it<5; it++){
        if(it<4)
            gfused1_k<false><<<dim3(16,BATCH),256,0,stream>>>(Abuf, BT1[it&1],
                Wl1a, Wl1b, Wx1a, Wx1b, We1a, xaB, BT1[(it+1)&1], uaB, ubB);
        else
            gfused1_k<true><<<dim3(16,BATCH),256,0,stream>>>(Abuf, BT1[it&1],
                Wl1a, Wl1b, Wx1a, Wx1b, We1a, xaB, BT1[(it+1)&1], uaB, ubB);
    }
    x2_k<<<dim3(16,BATCH),256,0,stream>>>(uaB, ubB, Wx2, x2B);
    binit_k<<<dim3(12,128,BATCH),256,0,stream>>>(g0, We2, BT2[0], 128);
    for(int it=0; it<5; it++){
        if(it<4)
            gfused2_k<false><<<dim3(16,BATCH),256,0,stream>>>(Abuf, BT2[it&1],
                Wl2, x2B, We2, WQ, BT2[(it+1)&1], out);
        else
            gfused2_k<true><<<dim3(16,BATCH),256,0,stream>>>(Abuf, BT2[it&1],
                Wl2, x2B, We2, WQ, BT2[(it+1)&1], out);
    }
}